// Round 4
// baseline (30077.051 us; speedup 1.0000x reference)
//
#include <hip/hip_runtime.h>
#include <hip/hip_bf16.h>

typedef short  short8  __attribute__((ext_vector_type(8)));
typedef float  float4v __attribute__((ext_vector_type(4)));

#define NSTEPS 60
#define ROWS   8             // trajectory rows per WG
#define GRID   256           // 2048 / ROWS -> one WG per CU, 2 resident
#define C1S    518           // padded f32 stride for c1s

// Tsit5 coefficients premultiplied by H = 1/60
constexpr double Hd = 1.0 / 60.0;
constexpr float HA1[1] = { (float)(Hd * 0.161) };
constexpr float HA2[2] = { (float)(Hd * -0.008480655492356989), (float)(Hd * 0.335480655492357) };
constexpr float HA3[3] = { (float)(Hd * 2.8971530571054935), (float)(Hd * -6.359448489975075),
                           (float)(Hd * 4.3622954328695815) };
constexpr float HA4[4] = { (float)(Hd * 5.325864828439257), (float)(Hd * -11.748883564062828),
                           (float)(Hd * 7.4955393428898365), (float)(Hd * -0.09249506636175525) };
constexpr float HA5[5] = { (float)(Hd * 5.86145544294642), (float)(Hd * -12.92096931784711),
                           (float)(Hd * 8.159367898576159), (float)(Hd * -0.071584973281401),
                           (float)(Hd * -0.028269050394068383) };
constexpr float HB6[6] = { (float)(Hd * 0.09646076681806523), (float)(Hd * 0.01),
                           (float)(Hd * 0.4798896504144996), (float)(Hd * 1.379008574103742),
                           (float)(Hd * -3.290069515436081), (float)(Hd * 2.324710524099774) };

__device__ __forceinline__ unsigned short f2bf(float f) {
    union { float f; unsigned u; } v; v.f = f;
    unsigned r = v.u + 0x7fffu + ((v.u >> 16) & 1u);   // RNE
    return (unsigned short)(r >> 16);
}

// Weight conversion: f32 row-major -> bf16 in MFMA-fragment-linear block layout.
// Block (ntile, kstep) = 1024 B; lane l holds W[n = ntile*16 + (l&15)]
// [k = kstep*32 + (l>>4)*8 .. +8]  (exact B-fragment of mfma_f32_16x16x32_bf16).
// ws layout (shorts): [W1y: 256 blks][W2: 512 blks][W3: 256 blks], 1 MB total.
__global__ void wconv(const float* __restrict__ W1, const float* __restrict__ W2,
                      const float* __restrict__ W3, unsigned short* __restrict__ ws) {
    int g = blockIdx.x * blockDim.x + threadIdx.x;   // chunk id, 0..65535
    int blk = g >> 6, l = g & 63;
    const float* src;
    if (blk < 256) {                 // W1y: N=512, K=256 (first 256 input cols of W1)
        int b = blk; int nt = b >> 3, ks = b & 7;
        int n = nt * 16 + (l & 15), k = ks * 32 + (l >> 4) * 8;
        src = W1 + n * 512 + k;
    } else if (blk < 768) {          // W2: N=512, K=512
        int b = blk - 256; int nt = b >> 4, ks = b & 15;
        int n = nt * 16 + (l & 15), k = ks * 32 + (l >> 4) * 8;
        src = W2 + n * 512 + k;
    } else {                         // W3: N=256, K=512
        int b = blk - 768; int nt = b >> 4, ks = b & 15;
        int n = nt * 16 + (l & 15), k = ks * 32 + (l >> 4) * 8;
        src = W3 + n * 512 + k;
    }
    short8 v;
#pragma unroll
    for (int j = 0; j < 8; ++j) v[j] = (short)f2bf(src[j]);
    *(((short8*)ws) + g) = v;
}

// A-fragments from XOR-swizzled LDS (rows 8-15 duplicate 0-7); B-fragments
// streamed from global (fragment-linear). NT=2, no manual pipeline: register
// pressure stays under 128 and TLP (2 WGs/CU) hides the load latency.
template<int KDIM>
__device__ __forceinline__ void mfma2(const unsigned short* __restrict__ lds, int stride,
                                      const short8* __restrict__ wb, int ntg0, int lane,
                                      float4v* acc) {
    constexpr int KS = KDIM / 32;
    const int vrow = lane & 7;                // A rows 8-15 -> duplicates of 0-7
    const int koff = (lane >> 4) * 8;
    const int rm   = vrow << 3;               // XOR swizzle in 8-short units
    const short8* wp = wb + (size_t)ntg0 * KS * 64 + lane;
#pragma unroll
    for (int ks = 0; ks < KS; ++ks) {
        short8 a  = *(const short8*)(lds + vrow * stride + (((ks * 32) + koff) ^ rm));
        short8 b0 = wp[(size_t)ks * 64];
        short8 b1 = wp[(size_t)(KS + ks) * 64];
        acc[0] = __builtin_amdgcn_mfma_f32_16x16x32_bf16(a, b0, acc[0], 0, 0, 0);
        acc[1] = __builtin_amdgcn_mfma_f32_16x16x32_bf16(a, b1, acc[1], 0, 0, 0);
    }
}

// One WG = 8 trajectory rows, 8 waves, entire 60-step integration. No inter-WG comm.
__global__ void __launch_bounds__(512, 4) odeint(
        const float* __restrict__ x0, const float* __restrict__ uf,
        const float* __restrict__ W1, const float* __restrict__ b1,
        const float* __restrict__ b2, const float* __restrict__ b3,
        const unsigned short* __restrict__ ws, float* __restrict__ out) {
    __shared__ unsigned short xb[8 * 256];    // stage input, bf16, XOR-swizzled (4 KB)
    __shared__ unsigned short h1[8 * 512];    // hidden 1 (8 KB)
    __shared__ unsigned short h2[8 * 512];    // hidden 2 (8 KB)
    __shared__ float c1s[8 * C1S];            // W1u@u + b1 per row (16.6 KB)

    const int tid  = threadIdx.x;
    const int wave = tid >> 6, lane = tid & 63;
    const int r0   = blockIdx.x * ROWS;
    const bool forced = (r0 < 1024);          // rows stacked [forced; unforced]

    // ---- stage u (f32) into h1-as-scratch (8 KB = sizeof(h1)) ----
    float* utmp = (float*)h1;
    {
        float4v* ud = (float4v*)utmp;
        for (int i = tid; i < ROWS * 64; i += 512) {
            float4v v = {0.f, 0.f, 0.f, 0.f};
            if (forced) v = *(const float4v*)(uf + (size_t)(r0 + (i >> 6)) * 256 + (i & 63) * 4);
            ud[i] = v;
        }
    }
    __syncthreads();

    // ---- c1 = W1u @ u + b1 (one-time, f32 VALU; utmp reads broadcast) ----
    {
        int n = tid;                           // thread owns neuron n for all 8 rows
        float acc8[ROWS];
        float bb = b1[n];
#pragma unroll
        for (int r = 0; r < ROWS; ++r) acc8[r] = bb;
        const float* wrow = W1 + n * 512 + 256;
        for (int k = 0; k < 256; ++k) {
            float w = wrow[k];
#pragma unroll
            for (int r = 0; r < ROWS; ++r) acc8[r] += w * utmp[r * 256 + k];
        }
#pragma unroll
        for (int r = 0; r < ROWS; ++r) c1s[r * C1S + n] = acc8[r];
    }
    __syncthreads();                           // utmp dead; h1 free for bf16 use

    // ---- biases in registers (per-lane slices) ----
    float breg2[4], breg3[2];
#pragma unroll
    for (int j = 0; j < 4; ++j) breg2[j] = b2[(wave * 4 + j) * 16 + (lane & 15)];
#pragma unroll
    for (int nt = 0; nt < 2; ++nt) breg3[nt] = b3[(wave * 2 + nt) * 16 + (lane & 15)];

    // ---- y and k1..k6 in registers, C/D fragment layout (lanes 32-63 = dup rows) ----
    float ybr[8];
    float kreg[6][8];
#pragma unroll
    for (int e = 0; e < 8; ++e) {
        int nt = e >> 2, r = e & 3;
        int vrow = ((lane >> 4) * 4 + r) & 7;
        int n    = (wave * 2 + nt) * 16 + (lane & 15);
        ybr[e] = x0[(size_t)((r0 + vrow) & 1023) * 256 + n];
    }

    const short8* wy1 = (const short8*)ws;
    const short8* w2  = (const short8*)(ws + 131072);   // +256 KB
    const short8* w3  = (const short8*)(ws + 393216);   // +768 KB

#define DO_STAGE(S, COEF) do {                                                          \
    {   /* write stage input x = y + sum COEF[j]*k_j  (rows 0-7 only) */                \
        _Pragma("unroll")                                                               \
        for (int e = 0; e < 8; ++e) {                                                   \
            int nt_ = e >> 2, r_ = e & 3;                                               \
            int row_ = (lane >> 4) * 4 + r_;                                            \
            int n_   = (wave * 2 + nt_) * 16 + (lane & 15);                             \
            float v_ = ybr[e];                                                          \
            _Pragma("unroll")                                                           \
            for (int j = 0; j < S; ++j) v_ += COEF[j] * kreg[j][e];                     \
            if (row_ < 8) xb[row_ * 256 + (n_ ^ (row_ << 3))] = f2bf(v_);               \
        }                                                                               \
    }                                                                                   \
    __syncthreads();  /* A: xb ready */                                                 \
    {   /* layer 1: K=256 from xb, +c1, relu -> h1; two NT=2 passes */                  \
        _Pragma("unroll")                                                               \
        for (int p = 0; p < 2; ++p) {                                                   \
            float4v a1[2] = {{0.f,0.f,0.f,0.f},{0.f,0.f,0.f,0.f}};                      \
            mfma2<256>(xb, 256, wy1, wave * 4 + p * 2, lane, a1);                       \
            _Pragma("unroll")                                                           \
            for (int nt = 0; nt < 2; ++nt) {                                            \
                int n_g = (wave * 4 + p * 2 + nt) * 16 + (lane & 15);                   \
                _Pragma("unroll")                                                       \
                for (int r = 0; r < 4; ++r) {                                           \
                    int row = (lane >> 4) * 4 + r;                                      \
                    if (row < 8) {                                                      \
                        float v = a1[nt][r] + c1s[row * C1S + n_g];                     \
                        h1[row * 512 + (n_g ^ (row << 3))] = f2bf(fmaxf(v, 0.f));       \
                    }                                                                   \
                }                                                                       \
            }                                                                           \
        }                                                                               \
    }                                                                                   \
    __syncthreads();  /* B: h1 ready */                                                 \
    {   /* layer 2: K=512 from h1, +b2, relu -> h2; two NT=2 passes */                  \
        _Pragma("unroll")                                                               \
        for (int p = 0; p < 2; ++p) {                                                   \
            float4v a2[2] = {{0.f,0.f,0.f,0.f},{0.f,0.f,0.f,0.f}};                      \
            mfma2<512>(h1, 512, w2, wave * 4 + p * 2, lane, a2);                        \
            _Pragma("unroll")                                                           \
            for (int nt = 0; nt < 2; ++nt) {                                            \
                int n_g = (wave * 4 + p * 2 + nt) * 16 + (lane & 15);                   \
                _Pragma("unroll")                                                       \
                for (int r = 0; r < 4; ++r) {                                           \
                    int row = (lane >> 4) * 4 + r;                                      \
                    if (row < 8) {                                                      \
                        float v = a2[nt][r] + breg2[p * 2 + nt];                        \
                        h2[row * 512 + (n_g ^ (row << 3))] = f2bf(fmaxf(v, 0.f));       \
                    }                                                                   \
                }                                                                       \
            }                                                                           \
        }                                                                               \
    }                                                                                   \
    __syncthreads();  /* D: h2 ready */                                                 \
    {   /* layer 3: K=512 from h2, +b3 -> kreg[S] (all lanes; 32-63 hold dups) */       \
        float4v a3[2] = {{0.f,0.f,0.f,0.f},{0.f,0.f,0.f,0.f}};                          \
        mfma2<512>(h2, 512, w3, wave * 2, lane, a3);                                    \
        _Pragma("unroll")                                                               \
        for (int nt = 0; nt < 2; ++nt) {                                                \
            _Pragma("unroll")                                                           \
            for (int r = 0; r < 4; ++r) {                                               \
                kreg[S][nt * 4 + r] = a3[nt][r] + breg3[nt];                            \
            }                                                                           \
        }                                                                               \
    }                                                                                   \
} while (0)

    for (int step = 0; step < NSTEPS; ++step) {
        DO_STAGE(0, HA1);
        DO_STAGE(1, HA1);
        DO_STAGE(2, HA2);
        DO_STAGE(3, HA3);
        DO_STAGE(4, HA4);
        DO_STAGE(5, HA5);
        {   // y update (pure registers, no barrier needed)
#pragma unroll
            for (int e = 0; e < 8; ++e) {
                float v = ybr[e];
#pragma unroll
                for (int j = 0; j < 6; ++j) v += HB6[j] * kreg[j][e];
                ybr[e] = v;
            }
        }
    }
#undef DO_STAGE

#pragma unroll
    for (int e = 0; e < 8; ++e) {
        int nt = e >> 2, r = e & 3;
        int row = (lane >> 4) * 4 + r;
        int n   = (wave * 2 + nt) * 16 + (lane & 15);
        if (row < 8) out[(size_t)(r0 + row) * 256 + n] = ybr[e];
    }
}

extern "C" void kernel_launch(void* const* d_in, const int* in_sizes, int n_in,
                              void* d_out, int out_size, void* d_ws, size_t ws_size,
                              hipStream_t stream) {
    const float* x0 = (const float*)d_in[0];
    const float* uf = (const float*)d_in[1];
    const float* W1 = (const float*)d_in[2];
    const float* b1 = (const float*)d_in[3];
    const float* W2 = (const float*)d_in[4];
    const float* b2 = (const float*)d_in[5];
    const float* W3 = (const float*)d_in[6];
    const float* b3 = (const float*)d_in[7];
    unsigned short* ws = (unsigned short*)d_ws;   // 1 MB bf16 weights, rebuilt every call

    wconv<<<128, 512, 0, stream>>>(W1, W2, W3, ws);
    odeint<<<GRID, 512, 0, stream>>>(x0, uf, W1, b1, b2, b3, ws, (float*)d_out);
}